// Round 1
// baseline (311.873 us; speedup 1.0000x reference)
//
#include <hip/hip_runtime.h>

typedef unsigned short u16;
typedef short bf16x8 __attribute__((ext_vector_type(8)));
typedef float f32x4 __attribute__((ext_vector_type(4)));

#define LOG2E 1.44269504f

__device__ __forceinline__ u16 f2b(float f) {
  union { float f; unsigned u; } v; v.f = f;
  unsigned r = v.u + 0x7FFFu + ((v.u >> 16) & 1u);
  return (u16)(r >> 16);
}

// ---------------- cast x: fp32 -> bf16, 4 elems/thread ----------------
__global__ __launch_bounds__(256) void k_cast(const float* __restrict__ in, u16* __restrict__ out) {
  int i = blockIdx.x * 256 + threadIdx.x;
  float4 v = ((const float4*)in)[i];
  ushort4 o;
  o.x = f2b(v.x); o.y = f2b(v.y); o.z = f2b(v.z); o.w = f2b(v.w);
  ((ushort4*)out)[i] = o;
}

// ------------- transpose+cast weights: in[R][C] fp32 -> out[C][R] bf16 -------------
__global__ __launch_bounds__(256) void k_transpose(const float* __restrict__ in, u16* __restrict__ out,
                                                   int R, int C) {
  __shared__ float tile[32][33];
  int c0 = blockIdx.x * 32, r0 = blockIdx.y * 32;
  int tx = threadIdx.x, ty = threadIdx.y;
#pragma unroll
  for (int i = 0; i < 32; i += 8)
    tile[ty + i][tx] = in[(size_t)(r0 + ty + i) * C + c0 + tx];
  __syncthreads();
#pragma unroll
  for (int i = 0; i < 32; i += 8)
    out[(size_t)(c0 + ty + i) * R + r0 + tx] = f2b(tile[tx][ty + i]);
}

// ------------- GEMM: C[M][N] fp32 = A[M][K]bf16 * Bt[N][K]bf16^T, 128x128 tile -------------
template<int Nsz, int Ksz>
__global__ __launch_bounds__(256) void k_gemm_bt(const u16* __restrict__ A, const u16* __restrict__ Bt,
                                                 float* __restrict__ C) {
  __shared__ u16 As[128 * 32];
  __shared__ u16 Bs[128 * 32];
  const int tid = threadIdx.x;
  const int l = tid & 63, w = tid >> 6;
  const int wm = w >> 1, wn = w & 1;
  const int m0 = blockIdx.x * 128, n0 = blockIdx.y * 128;
  const int rg = l >> 4, cl = l & 15;
  f32x4 acc[4][4] = {};
  for (int k0 = 0; k0 < Ksz; k0 += 32) {
#pragma unroll
    for (int i = 0; i < 2; i++) {
      int c = tid + i * 256;
      int row = c >> 2, off = c & 3;
      uint4 va = *(const uint4*)(A + (size_t)(m0 + row) * Ksz + k0 + off * 8);
      uint4 vb = *(const uint4*)(Bt + (size_t)(n0 + row) * Ksz + k0 + off * 8);
      unsigned ba = (unsigned)((row * 64 + off * 16) ^ ((row & 7) << 4));
      *(uint4*)((char*)As + ba) = va;
      *(uint4*)((char*)Bs + ba) = vb;
    }
    __syncthreads();
    bf16x8 aF[4], bF[4];
#pragma unroll
    for (int m = 0; m < 4; m++) {
      int row = wm * 64 + m * 16 + cl;
      unsigned ba = (unsigned)((row * 64 + rg * 16) ^ ((row & 7) << 4));
      aF[m] = *(const bf16x8*)((char*)As + ba);
    }
#pragma unroll
    for (int n = 0; n < 4; n++) {
      int row = wn * 64 + n * 16 + cl;
      unsigned ba = (unsigned)((row * 64 + rg * 16) ^ ((row & 7) << 4));
      bF[n] = *(const bf16x8*)((char*)Bs + ba);
    }
#pragma unroll
    for (int m = 0; m < 4; m++)
#pragma unroll
      for (int n = 0; n < 4; n++)
        acc[m][n] = __builtin_amdgcn_mfma_f32_16x16x32_bf16(aF[m], bF[n], acc[m][n], 0, 0, 0);
    __syncthreads();
  }
#pragma unroll
  for (int m = 0; m < 4; m++)
#pragma unroll
    for (int n = 0; n < 4; n++)
#pragma unroll
      for (int r = 0; r < 4; r++)
        C[(size_t)(m0 + wm * 64 + m * 16 + rg * 4 + r) * Nsz + n0 + wn * 64 + n * 16 + cl] = acc[m][n][r];
}

// ------------- RoPE Q/K from fp32 qkv; scatter to head-major bf16 -------------
__global__ __launch_bounds__(256) void k_rope(const float* __restrict__ qkv, const float* __restrict__ cs,
                                              const float* __restrict__ sn, u16* __restrict__ Qb,
                                              u16* __restrict__ Kb) {
  int idx = blockIdx.x * 256 + threadIdx.x;  // over 4096*1536
  int c = idx % 1536;
  int row = idx / 1536;
  int b = row >> 11, t = row & 2047;
  int d = c & 63;
  const float* rp = qkv + (size_t)row * 2048;
  float x = rp[c];
  float xr = (d < 32) ? -rp[c + 32] : rp[c - 32];
  float val = x * cs[t * 64 + d] + xr * sn[t * 64 + d];
  u16 ov = f2b(val);
  if (c < 1024) {
    int h = c >> 6;
    Qb[((size_t)(b * 16 + h) * 2048 + t) * 64 + d] = ov;
  } else {
    int kk = (c - 1024) >> 6;
    Kb[((size_t)(b * 8 + kk) * 2048 + t) * 64 + d] = ov;
  }
}

// ------------- V transpose: qkv fp32 V-part -> Vt[b*8+kh][64][2048] bf16 -------------
__global__ __launch_bounds__(256) void k_vtrans(const float* __restrict__ qkv, u16* __restrict__ Vt) {
  __shared__ u16 tile[64][65];
  int blk = blockIdx.x;
  int t0 = (blk & 31) * 64;
  int bh = blk >> 5;  // b*8+kh
  int tx = threadIdx.x & 63, ty = threadIdx.x >> 6;
  const float* src = qkv + (size_t)((bh >> 3) * 2048 + t0) * 2048 + 1536 + (bh & 7) * 64;
#pragma unroll
  for (int i = 0; i < 64; i += 4)
    tile[ty + i][tx] = f2b(src[(size_t)(ty + i) * 2048 + tx]);
  __syncthreads();
  u16* dst = Vt + (size_t)bh * 64 * 2048 + t0;
#pragma unroll
  for (int i = 0; i < 64; i += 4)
    dst[(size_t)(ty + i) * 2048 + tx] = tile[tx][ty + i];
}

// ------------- causal flash attention: 1 wave per 16-row Q block -------------
__global__ __launch_bounds__(256) void k_flash(const u16* __restrict__ Qb, const u16* __restrict__ Kb,
                                               const u16* __restrict__ Vt, u16* __restrict__ Ob) {
  __shared__ u16 Plds[4][16 * 40];
  const int tid = threadIdx.x;
  const int l = tid & 63, w = tid >> 6;
  const int gw = blockIdx.x * 4 + w;
  const int qb = gw & 127, h = (gw >> 7) & 15, b = gw >> 11;
  const int kh = h >> 1;
  const int q0 = qb * 16;
  const int rg = l >> 4, cl = l & 15;
  const u16* Qp = Qb + ((size_t)(b * 16 + h) * 2048 + q0 + cl) * 64 + rg * 8;
  const u16* Kp = Kb + (size_t)(b * 8 + kh) * 2048 * 64;
  const u16* Vp = Vt + (size_t)(b * 8 + kh) * 64 * 2048;
  bf16x8 qf0 = *(const bf16x8*)(Qp);
  bf16x8 qf1 = *(const bf16x8*)(Qp + 32);
  f32x4 o[4] = {};
  float m_[4], l_[4];
#pragma unroll
  for (int r = 0; r < 4; r++) { m_[r] = -1e30f; l_[r] = 0.f; }
  const int nt = q0 / 32 + 1;
  u16* Pw = &Plds[w][0];
  for (int t = 0; t < nt; t++) {
    const int k0 = t * 32;
    f32x4 sc[2] = {};
#pragma unroll
    for (int n = 0; n < 2; n++) {
      const u16* kp = Kp + (size_t)(k0 + n * 16 + cl) * 64 + rg * 8;
      bf16x8 kf0 = *(const bf16x8*)(kp);
      bf16x8 kf1 = *(const bf16x8*)(kp + 32);
      sc[n] = __builtin_amdgcn_mfma_f32_16x16x32_bf16(qf0, kf0, sc[n], 0, 0, 0);
      sc[n] = __builtin_amdgcn_mfma_f32_16x16x32_bf16(qf1, kf1, sc[n], 0, 0, 0);
    }
    const bool edge = (k0 + 31 > q0);
#pragma unroll
    for (int n = 0; n < 2; n++) {
      int kpos = k0 + n * 16 + cl;
#pragma unroll
      for (int r = 0; r < 4; r++) {
        float sv = sc[n][r] * 0.125f;
        if (edge && kpos > q0 + rg * 4 + r) sv = -1e30f;
        sc[n][r] = sv;
      }
    }
#pragma unroll
    for (int r = 0; r < 4; r++) {
      float mx = fmaxf(sc[0][r], sc[1][r]);
      mx = fmaxf(mx, __shfl_xor(mx, 1));
      mx = fmaxf(mx, __shfl_xor(mx, 2));
      mx = fmaxf(mx, __shfl_xor(mx, 4));
      mx = fmaxf(mx, __shfl_xor(mx, 8));
      float mnew = fmaxf(m_[r], mx);
      float alpha = exp2f((m_[r] - mnew) * LOG2E);
      m_[r] = mnew;
      l_[r] *= alpha;
      o[0][r] *= alpha; o[1][r] *= alpha; o[2][r] *= alpha; o[3][r] *= alpha;
      float p0 = exp2f((sc[0][r] - mnew) * LOG2E);
      float p1 = exp2f((sc[1][r] - mnew) * LOG2E);
      sc[0][r] = p0; sc[1][r] = p1;
      float su = p0 + p1;
      su += __shfl_xor(su, 1);
      su += __shfl_xor(su, 2);
      su += __shfl_xor(su, 4);
      su += __shfl_xor(su, 8);
      l_[r] += su;
    }
#pragma unroll
    for (int n = 0; n < 2; n++)
#pragma unroll
      for (int r = 0; r < 4; r++)
        Pw[(rg * 4 + r) * 40 + n * 16 + cl] = f2b(sc[n][r]);
    bf16x8 pa = *(const bf16x8*)(Pw + cl * 40 + rg * 8);
#pragma unroll
    for (int c = 0; c < 4; c++) {
      bf16x8 vf = *(const bf16x8*)(Vp + (size_t)(c * 16 + cl) * 2048 + k0 + rg * 8);
      o[c] = __builtin_amdgcn_mfma_f32_16x16x32_bf16(pa, vf, o[c], 0, 0, 0);
    }
  }
#pragma unroll
  for (int r = 0; r < 4; r++) l_[r] = 1.0f / l_[r];
  size_t obase = (size_t)(b * 2048 + q0) * 1024 + h * 64;
#pragma unroll
  for (int c = 0; c < 4; c++)
#pragma unroll
    for (int r = 0; r < 4; r++)
      Ob[obase + (size_t)(rg * 4 + r) * 1024 + c * 16 + cl] = f2b(o[c][r] * l_[r]);
}

extern "C" void kernel_launch(void* const* d_in, const int* in_sizes, int n_in,
                              void* d_out, int out_size, void* d_ws, size_t ws_size,
                              hipStream_t stream) {
  const float* x = (const float*)d_in[0];
  const float* cs = (const float*)d_in[1];
  const float* sn = (const float*)d_in[2];
  const float* w_qkv = (const float*)d_in[3];
  const float* w_out = (const float*)d_in[4];
  float* out = (float*)d_out;
  char* ws = (char*)d_ws;

  u16* Xb   = (u16*)(ws + (size_t)(0u) );          // 8 MB  [4096][1024]
  u16* Wqt  = (u16*)(ws + ((size_t)8u << 20));     // 4 MB  [2048][1024]
  u16* Wot  = (u16*)(ws + ((size_t)12u << 20));    // 2 MB  [1024][1024]
  float* qkv = (float*)(ws + ((size_t)14u << 20)); // 32 MB [4096][2048]
  u16* Qb   = (u16*)(ws + ((size_t)46u << 20));    // 8 MB  [2][16][2048][64]
  u16* Kb   = (u16*)(ws + ((size_t)54u << 20));    // 4 MB  [2][8][2048][64]
  u16* Vt   = (u16*)(ws + ((size_t)58u << 20));    // 4 MB  [2][8][64][2048]
  u16* Ob   = (u16*)(ws + ((size_t)62u << 20));    // 8 MB  [4096][1024]

  k_cast<<<4096, 256, 0, stream>>>(x, Xb);
  k_transpose<<<dim3(2048 / 32, 1024 / 32), dim3(32, 8), 0, stream>>>(w_qkv, Wqt, 1024, 2048);
  k_transpose<<<dim3(1024 / 32, 1024 / 32), dim3(32, 8), 0, stream>>>(w_out, Wot, 1024, 1024);
  k_gemm_bt<2048, 1024><<<dim3(32, 16), 256, 0, stream>>>(Xb, Wqt, qkv);
  k_rope<<<24576, 256, 0, stream>>>(qkv, cs, sn, Qb, Kb);
  k_vtrans<<<512, 256, 0, stream>>>(qkv, Vt);
  k_flash<<<1024, 256, 0, stream>>>(Qb, Kb, Vt, Ob);
  k_gemm_bt<1024, 1024><<<dim3(32, 8), 256, 0, stream>>>(Ob, Wot, out);
}

// Round 2
// 180.799 us; speedup vs baseline: 1.7250x; 1.7250x over previous
//
#include <hip/hip_runtime.h>

typedef unsigned short u16;
typedef unsigned int u32;
typedef short bf16x8 __attribute__((ext_vector_type(8)));
typedef float f32x4 __attribute__((ext_vector_type(4)));
typedef float f32x16 __attribute__((ext_vector_type(16)));

#define LOG2E 1.44269504f

__device__ __forceinline__ u16 f2b(float f) {
  union { float f; unsigned u; } v; v.f = f;
  unsigned r = v.u + 0x7FFFu + ((v.u >> 16) & 1u);
  return (u16)(r >> 16);
}

// pack two f32 -> one u32 of 2 bf16 (round-half-up)
__device__ __forceinline__ u32 pk2(float a, float b) {
  union { float f; u32 u; } x, y; x.f = a; y.f = b;
  return ((x.u + 0x8000u) >> 16) | ((y.u + 0x8000u) & 0xFFFF0000u);
}

// v_permlane32_swap: x' = {x.lo32, y.lo32-of-partner}, y' = {x.hi32-of-partner, y.hi32}
__device__ __forceinline__ void plswap(u32& x, u32& y) {
#if __has_builtin(__builtin_amdgcn_permlane32_swap)
  typedef int v2i __attribute__((ext_vector_type(2)));
  v2i r = __builtin_amdgcn_permlane32_swap((int)x, (int)y, false, false);
  x = (u32)r[0]; y = (u32)r[1];
#else
  u32 sx = (u32)__shfl_xor((int)x, 32, 64);
  u32 sy = (u32)__shfl_xor((int)y, 32, 64);
  bool hi = (threadIdx.x & 63) >= 32;
  u32 nx = hi ? sy : x;
  u32 ny = hi ? y : sx;
  x = nx; y = ny;
#endif
}

// ---------------- cast x: fp32 -> bf16, 4 elems/thread ----------------
__global__ __launch_bounds__(256) void k_cast(const float* __restrict__ in, u16* __restrict__ out) {
  int i = blockIdx.x * 256 + threadIdx.x;
  float4 v = ((const float4*)in)[i];
  ushort4 o;
  o.x = f2b(v.x); o.y = f2b(v.y); o.z = f2b(v.z); o.w = f2b(v.w);
  ((ushort4*)out)[i] = o;
}

// ------------- transpose+cast weights: in[R][C] fp32 -> out[C][R] bf16 -------------
__global__ __launch_bounds__(256) void k_transpose(const float* __restrict__ in, u16* __restrict__ out,
                                                   int R, int C) {
  __shared__ float tile[32][33];
  int c0 = blockIdx.x * 32, r0 = blockIdx.y * 32;
  int tx = threadIdx.x, ty = threadIdx.y;
#pragma unroll
  for (int i = 0; i < 32; i += 8)
    tile[ty + i][tx] = in[(size_t)(r0 + ty + i) * C + c0 + tx];
  __syncthreads();
#pragma unroll
  for (int i = 0; i < 32; i += 8)
    out[(size_t)(c0 + ty + i) * R + r0 + tx] = f2b(tile[tx][ty + i]);
}

// ------------- GEMM: C[M][N] fp32 = A[M][K]bf16 * Bt[N][K]bf16^T, 128x128 tile -------------
template<int Nsz, int Ksz>
__global__ __launch_bounds__(256) void k_gemm_bt(const u16* __restrict__ A, const u16* __restrict__ Bt,
                                                 float* __restrict__ C) {
  __shared__ u16 As[128 * 32];
  __shared__ u16 Bs[128 * 32];
  const int tid = threadIdx.x;
  const int l = tid & 63, w = tid >> 6;
  const int wm = w >> 1, wn = w & 1;
  const int m0 = blockIdx.x * 128, n0 = blockIdx.y * 128;
  const int rg = l >> 4, cl = l & 15;
  f32x4 acc[4][4] = {};
  for (int k0 = 0; k0 < Ksz; k0 += 32) {
#pragma unroll
    for (int i = 0; i < 2; i++) {
      int c = tid + i * 256;
      int row = c >> 2, off = c & 3;
      uint4 va = *(const uint4*)(A + (size_t)(m0 + row) * Ksz + k0 + off * 8);
      uint4 vb = *(const uint4*)(Bt + (size_t)(n0 + row) * Ksz + k0 + off * 8);
      unsigned ba = (unsigned)((row * 64 + off * 16) ^ ((row & 7) << 4));
      *(uint4*)((char*)As + ba) = va;
      *(uint4*)((char*)Bs + ba) = vb;
    }
    __syncthreads();
    bf16x8 aF[4], bF[4];
#pragma unroll
    for (int m = 0; m < 4; m++) {
      int row = wm * 64 + m * 16 + cl;
      unsigned ba = (unsigned)((row * 64 + rg * 16) ^ ((row & 7) << 4));
      aF[m] = *(const bf16x8*)((char*)As + ba);
    }
#pragma unroll
    for (int n = 0; n < 4; n++) {
      int row = wn * 64 + n * 16 + cl;
      unsigned ba = (unsigned)((row * 64 + rg * 16) ^ ((row & 7) << 4));
      bF[n] = *(const bf16x8*)((char*)Bs + ba);
    }
#pragma unroll
    for (int m = 0; m < 4; m++)
#pragma unroll
      for (int n = 0; n < 4; n++)
        acc[m][n] = __builtin_amdgcn_mfma_f32_16x16x32_bf16(aF[m], bF[n], acc[m][n], 0, 0, 0);
    __syncthreads();
  }
#pragma unroll
  for (int m = 0; m < 4; m++)
#pragma unroll
    for (int n = 0; n < 4; n++)
#pragma unroll
      for (int r = 0; r < 4; r++)
        C[(size_t)(m0 + wm * 64 + m * 16 + rg * 4 + r) * Nsz + n0 + wn * 64 + n * 16 + cl] = acc[m][n][r];
}

// ------------- RoPE Q/K from fp32 qkv; scatter to head-major bf16 (Q scaled by 1/8) -------------
__global__ __launch_bounds__(256) void k_rope(const float* __restrict__ qkv, const float* __restrict__ cs,
                                              const float* __restrict__ sn, u16* __restrict__ Qb,
                                              u16* __restrict__ Kb) {
  int idx = blockIdx.x * 256 + threadIdx.x;  // over 4096*1536
  int c = idx % 1536;
  int row = idx / 1536;
  int b = row >> 11, t = row & 2047;
  int d = c & 63;
  const float* rp = qkv + (size_t)row * 2048;
  float x = rp[c];
  float xr = (d < 32) ? -rp[c + 32] : rp[c - 32];
  float val = x * cs[t * 64 + d] + xr * sn[t * 64 + d];
  if (c < 1024) {
    int h = c >> 6;
    Qb[((size_t)(b * 16 + h) * 2048 + t) * 64 + d] = f2b(val * 0.125f);
  } else {
    int kk = (c - 1024) >> 6;
    Kb[((size_t)(b * 8 + kk) * 2048 + t) * 64 + d] = f2b(val);
  }
}

// ------------- V transpose: qkv fp32 V-part -> Vt[b*8+kh][64][2048] bf16 -------------
__global__ __launch_bounds__(256) void k_vtrans(const float* __restrict__ qkv, u16* __restrict__ Vt) {
  __shared__ u16 tile[64][65];
  int blk = blockIdx.x;
  int t0 = (blk & 31) * 64;
  int bh = blk >> 5;  // b*8+kh
  int tx = threadIdx.x & 63, ty = threadIdx.x >> 6;
  const float* src = qkv + (size_t)((bh >> 3) * 2048 + t0) * 2048 + 1536 + (bh & 7) * 64;
#pragma unroll
  for (int i = 0; i < 64; i += 4)
    tile[ty + i][tx] = f2b(src[(size_t)(ty + i) * 2048 + tx]);
  __syncthreads();
  u16* dst = Vt + (size_t)bh * 64 * 2048 + t0;
#pragma unroll
  for (int i = 0; i < 64; i += 4)
    dst[(size_t)(ty + i) * 2048 + tx] = tile[tx][ty + i];
}

// ------------- causal flash attention v2: 1 wave per 32-row Q block, 32x32 MFMA -------------
// swapped QK^T (S^T = K·Q^T) -> in-register softmax; P->PV via pk2+permlane32_swap; O^T via LDS transpose
__global__ __launch_bounds__(256) void k_flash2(const u16* __restrict__ Qb, const u16* __restrict__ Kb,
                                                const u16* __restrict__ Vt, u16* __restrict__ Ob) {
  __shared__ u32 otile[4][32 * 36];
  const int tid = threadIdx.x;
  const int l = tid & 63, w = tid >> 6;
  const int gw = blockIdx.x * 4 + w;   // 2048 waves
  const int bh = gw & 31;
  const int qt = 63 - (gw >> 5);       // descending work: long waves launch first
  const int b = bh >> 4, h = bh & 15, kh = h >> 1;
  const int q0 = qt * 32;
  const int lq = l & 31, hi = l >> 5;
  const int q = q0 + lq;

  const u16* Qp = Qb + ((size_t)(b * 16 + h) * 2048 + q) * 64 + hi * 8;
  const u16* Kp = Kb + (size_t)(b * 8 + kh) * 2048 * 64 + (size_t)lq * 64 + hi * 8;
  const u16* Vp = Vt + (size_t)(b * 8 + kh) * 64 * 2048 + (size_t)lq * 2048 + hi * 8;

  bf16x8 qf[4];
#pragma unroll
  for (int ks = 0; ks < 4; ks++) qf[ks] = *(const bf16x8*)(Qp + ks * 16);

  f32x16 oa[2] = {};
  float m = -3e38f, lsum = 0.f;
  const int nt = (q0 + 95) >> 6;   // ceil((q0+32)/64)

  for (int t = 0; t < nt; t++) {
    const int kvb = t * 64;
    // ---- QK^T: S^T[kv][q], two 32-kv subtiles ----
    f32x16 s0 = {}, s1 = {};
    bf16x8 kf0[4], kf1[4];
#pragma unroll
    for (int ks = 0; ks < 4; ks++) {
      kf0[ks] = *(const bf16x8*)(Kp + (size_t)kvb * 64 + ks * 16);
      kf1[ks] = *(const bf16x8*)(Kp + (size_t)(kvb + 32) * 64 + ks * 16);
    }
    __builtin_amdgcn_s_setprio(1);
#pragma unroll
    for (int ks = 0; ks < 4; ks++) {
      s0 = __builtin_amdgcn_mfma_f32_32x32x16_bf16(kf0[ks], qf[ks], s0, 0, 0, 0);
      s1 = __builtin_amdgcn_mfma_f32_32x32x16_bf16(kf1[ks], qf[ks], s1, 0, 0, 0);
    }
    __builtin_amdgcn_s_setprio(0);

    // ---- causal mask (last tile only: KVBLK=64 > QBLK=32 so it always needs it) ----
    if (t == nt - 1) {
#pragma unroll
      for (int r = 0; r < 16; r++) {
        int kvr = kvb + (r & 3) + 8 * (r >> 2) + 4 * hi;
        if (kvr > q) s0[r] = -3e38f;
        if (kvr + 32 > q) s1[r] = -3e38f;
      }
    }

    // ---- online softmax (per-lane row; partner lane l^32 holds the other 32 kv) ----
    float tr[16];
#pragma unroll
    for (int r = 0; r < 16; r++) tr[r] = fmaxf(s0[r], s1[r]);
#pragma unroll
    for (int st = 8; st >= 1; st >>= 1)
#pragma unroll
      for (int i = 0; i < st; i++) tr[i] = fmaxf(tr[i], tr[i + st]);
    float mx = fmaxf(tr[0], __shfl_xor(tr[0], 32, 64));
    float mnew = fmaxf(m, mx);
    float alpha = exp2f((m - mnew) * LOG2E);
    float mb = mnew * LOG2E;
#pragma unroll
    for (int r = 0; r < 16; r++) {
      s0[r] = exp2f(fmaf(s0[r], LOG2E, -mb));
      s1[r] = exp2f(fmaf(s1[r], LOG2E, -mb));
    }
#pragma unroll
    for (int r = 0; r < 16; r++) tr[r] = s0[r] + s1[r];
#pragma unroll
    for (int st = 8; st >= 1; st >>= 1)
#pragma unroll
      for (int i = 0; i < st; i++) tr[i] += tr[i + st];
    float ssum = tr[0] + __shfl_xor(tr[0], 32, 64);
    lsum = lsum * alpha + ssum;
    m = mnew;
#pragma unroll
    for (int r = 0; r < 16; r++) { oa[0][r] *= alpha; oa[1][r] *= alpha; }

    // ---- P -> bf16 B-fragments (pk2 + permlane32_swap), then PV: O^T += V^T · P ----
#pragma unroll
    for (int n = 0; n < 2; n++) {
      u32 aw[8];
#pragma unroll
      for (int j = 0; j < 8; j++) {
        float va = n ? s1[2 * j] : s0[2 * j];
        float vb = n ? s1[2 * j + 1] : s0[2 * j + 1];
        aw[j] = pk2(va, vb);
      }
      plswap(aw[0], aw[2]); plswap(aw[1], aw[3]);
      plswap(aw[4], aw[6]); plswap(aw[5], aw[7]);
      union { u32 u[4]; bf16x8 v; } p0, p1;
#pragma unroll
      for (int j = 0; j < 4; j++) { p0.u[j] = aw[j]; p1.u[j] = aw[4 + j]; }
      __builtin_amdgcn_s_setprio(1);
#pragma unroll
      for (int dt = 0; dt < 2; dt++) {
        bf16x8 vf0 = *(const bf16x8*)(Vp + dt * 65536 + kvb + n * 32);
        bf16x8 vf1 = *(const bf16x8*)(Vp + dt * 65536 + kvb + n * 32 + 16);
        oa[dt] = __builtin_amdgcn_mfma_f32_32x32x16_bf16(vf0, p0.v, oa[dt], 0, 0, 0);
        oa[dt] = __builtin_amdgcn_mfma_f32_32x32x16_bf16(vf1, p1.v, oa[dt], 0, 0, 0);
      }
      __builtin_amdgcn_s_setprio(0);
    }
  }

  // ---- epilogue: normalize, transpose O^T -> O via LDS, coalesced store ----
  float linv = 1.0f / lsum;
  u32* ot = otile[w];
#pragma unroll
  for (int dt = 0; dt < 2; dt++)
#pragma unroll
    for (int r = 0; r < 16; r += 2) {
      int d = dt * 32 + (r & 3) + 8 * (r >> 2) + 4 * hi;
      ot[lq * 36 + (d >> 1)] =
          (u32)f2b(oa[dt][r] * linv) | ((u32)f2b(oa[dt][r + 1] * linv) << 16);
    }
  __syncthreads();
  const u32* otr = otile[w];
#pragma unroll
  for (int i = 0; i < 16; i++) {
    int wd = i * 64 + l;
    int row = wd >> 5, col = wd & 31;
    u32 v = otr[row * 36 + col];
    *(u32*)(Ob + (size_t)(b * 2048 + q0 + row) * 1024 + h * 64 + col * 2) = v;
  }
}

extern "C" void kernel_launch(void* const* d_in, const int* in_sizes, int n_in,
                              void* d_out, int out_size, void* d_ws, size_t ws_size,
                              hipStream_t stream) {
  const float* x = (const float*)d_in[0];
  const float* cs = (const float*)d_in[1];
  const float* sn = (const float*)d_in[2];
  const float* w_qkv = (const float*)d_in[3];
  const float* w_out = (const float*)d_in[4];
  float* out = (float*)d_out;
  char* ws = (char*)d_ws;

  u16* Xb   = (u16*)(ws + (size_t)(0u) );          // 8 MB  [4096][1024]
  u16* Wqt  = (u16*)(ws + ((size_t)8u << 20));     // 4 MB  [2048][1024]
  u16* Wot  = (u16*)(ws + ((size_t)12u << 20));    // 2 MB  [1024][1024]
  float* qkv = (float*)(ws + ((size_t)14u << 20)); // 32 MB [4096][2048]
  u16* Qb   = (u16*)(ws + ((size_t)46u << 20));    // 8 MB  [2][16][2048][64]
  u16* Kb   = (u16*)(ws + ((size_t)54u << 20));    // 4 MB  [2][8][2048][64]
  u16* Vt   = (u16*)(ws + ((size_t)58u << 20));    // 4 MB  [2][8][64][2048]
  u16* Ob   = (u16*)(ws + ((size_t)62u << 20));    // 8 MB  [4096][1024]

  k_cast<<<4096, 256, 0, stream>>>(x, Xb);
  k_transpose<<<dim3(2048 / 32, 1024 / 32), dim3(32, 8), 0, stream>>>(w_qkv, Wqt, 1024, 2048);
  k_transpose<<<dim3(1024 / 32, 1024 / 32), dim3(32, 8), 0, stream>>>(w_out, Wot, 1024, 1024);
  k_gemm_bt<2048, 1024><<<dim3(32, 16), 256, 0, stream>>>(Xb, Wqt, qkv);
  k_rope<<<24576, 256, 0, stream>>>(qkv, cs, sn, Qb, Kb);
  k_vtrans<<<512, 256, 0, stream>>>(qkv, Vt);
  k_flash2<<<512, 256, 0, stream>>>(Qb, Kb, Vt, Ob);
  k_gemm_bt<1024, 1024><<<dim3(32, 8), 256, 0, stream>>>(Ob, Wot, out);
}

// Round 3
// 170.110 us; speedup vs baseline: 1.8334x; 1.0628x over previous
//
#include <hip/hip_runtime.h>

typedef unsigned short u16;
typedef unsigned int u32;
typedef short bf16x8 __attribute__((ext_vector_type(8)));
typedef float f32x4 __attribute__((ext_vector_type(4)));
typedef float f32x8v __attribute__((ext_vector_type(8)));
typedef float f32x16 __attribute__((ext_vector_type(16)));

#define LOG2E 1.44269504f

__device__ __forceinline__ u16 f2b(float f) {
  union { float f; unsigned u; } v; v.f = f;
  unsigned r = v.u + 0x7FFFu + ((v.u >> 16) & 1u);
  return (u16)(r >> 16);
}

// pack two f32 -> one u32 of 2 bf16 (round-half-up)
__device__ __forceinline__ u32 pk2(float a, float b) {
  union { float f; u32 u; } x, y; x.f = a; y.f = b;
  return ((x.u + 0x8000u) >> 16) | ((y.u + 0x8000u) & 0xFFFF0000u);
}

// v_permlane32_swap: x' = {x.lo32, y.lo32-of-partner}, y' = {x.hi32-of-partner, y.hi32}
__device__ __forceinline__ void plswap(u32& x, u32& y) {
#if __has_builtin(__builtin_amdgcn_permlane32_swap)
  typedef int v2i __attribute__((ext_vector_type(2)));
  v2i r = __builtin_amdgcn_permlane32_swap((int)x, (int)y, false, false);
  x = (u32)r[0]; y = (u32)r[1];
#else
  u32 sx = (u32)__shfl_xor((int)x, 32, 64);
  u32 sy = (u32)__shfl_xor((int)y, 32, 64);
  bool hi = (threadIdx.x & 63) >= 32;
  u32 nx = hi ? sy : x;
  u32 ny = hi ? y : sx;
  x = nx; y = ny;
#endif
}

// ---------------- cast x: fp32 -> bf16, 4 elems/thread ----------------
__global__ __launch_bounds__(256) void k_cast(const float* __restrict__ in, u16* __restrict__ out) {
  int i = blockIdx.x * 256 + threadIdx.x;
  float4 v = ((const float4*)in)[i];
  ushort4 o;
  o.x = f2b(v.x); o.y = f2b(v.y); o.z = f2b(v.z); o.w = f2b(v.w);
  ((ushort4*)out)[i] = o;
}

// ------------- transpose+cast weights: in[R][C] fp32 -> out[C][R] bf16 -------------
__global__ __launch_bounds__(256) void k_transpose(const float* __restrict__ in, u16* __restrict__ out,
                                                   int R, int C) {
  __shared__ float tile[32][33];
  int c0 = blockIdx.x * 32, r0 = blockIdx.y * 32;
  int tx = threadIdx.x, ty = threadIdx.y;
#pragma unroll
  for (int i = 0; i < 32; i += 8)
    tile[ty + i][tx] = in[(size_t)(r0 + ty + i) * C + c0 + tx];
  __syncthreads();
#pragma unroll
  for (int i = 0; i < 32; i += 8)
    out[(size_t)(c0 + ty + i) * R + r0 + tx] = f2b(tile[tx][ty + i]);
}

// ------------- GEMM: C[M][N] fp32 = A[M][K]bf16 * Bt[N][K]bf16^T, 128x128 tile -------------
template<int Nsz, int Ksz>
__global__ __launch_bounds__(256) void k_gemm_bt(const u16* __restrict__ A, const u16* __restrict__ Bt,
                                                 float* __restrict__ C) {
  __shared__ u16 As[128 * 32];
  __shared__ u16 Bs[128 * 32];
  const int tid = threadIdx.x;
  const int l = tid & 63, w = tid >> 6;
  const int wm = w >> 1, wn = w & 1;
  const int m0 = blockIdx.x * 128, n0 = blockIdx.y * 128;
  const int rg = l >> 4, cl = l & 15;
  f32x4 acc[4][4] = {};
  for (int k0 = 0; k0 < Ksz; k0 += 32) {
#pragma unroll
    for (int i = 0; i < 2; i++) {
      int c = tid + i * 256;
      int row = c >> 2, off = c & 3;
      uint4 va = *(const uint4*)(A + (size_t)(m0 + row) * Ksz + k0 + off * 8);
      uint4 vb = *(const uint4*)(Bt + (size_t)(n0 + row) * Ksz + k0 + off * 8);
      unsigned ba = (unsigned)((row * 64 + off * 16) ^ ((row & 7) << 4));
      *(uint4*)((char*)As + ba) = va;
      *(uint4*)((char*)Bs + ba) = vb;
    }
    __syncthreads();
    bf16x8 aF[4], bF[4];
#pragma unroll
    for (int m = 0; m < 4; m++) {
      int row = wm * 64 + m * 16 + cl;
      unsigned ba = (unsigned)((row * 64 + rg * 16) ^ ((row & 7) << 4));
      aF[m] = *(const bf16x8*)((char*)As + ba);
    }
#pragma unroll
    for (int n = 0; n < 4; n++) {
      int row = wn * 64 + n * 16 + cl;
      unsigned ba = (unsigned)((row * 64 + rg * 16) ^ ((row & 7) << 4));
      bF[n] = *(const bf16x8*)((char*)Bs + ba);
    }
#pragma unroll
    for (int m = 0; m < 4; m++)
#pragma unroll
      for (int n = 0; n < 4; n++)
        acc[m][n] = __builtin_amdgcn_mfma_f32_16x16x32_bf16(aF[m], bF[n], acc[m][n], 0, 0, 0);
    __syncthreads();
  }
#pragma unroll
  for (int m = 0; m < 4; m++)
#pragma unroll
    for (int n = 0; n < 4; n++)
#pragma unroll
      for (int r = 0; r < 4; r++)
        C[(size_t)(m0 + wm * 64 + m * 16 + rg * 4 + r) * Nsz + n0 + wn * 64 + n * 16 + cl] = acc[m][n][r];
}

// ------------- RoPE Q/K (vectorized x8); scatter to head-major bf16 (Q scaled by 1/8) -------------
__global__ __launch_bounds__(256) void k_rope(const float* __restrict__ qkv, const float* __restrict__ cs,
                                              const float* __restrict__ sn, u16* __restrict__ Qb,
                                              u16* __restrict__ Kb) {
  int idx = blockIdx.x * 256 + threadIdx.x;  // over 4096*192 8-elem chunks
  int c8 = idx % 192;
  int row = idx / 192;
  int c = c8 * 8;
  int b = row >> 11, t = row & 2047;
  int d = c & 63;
  const float* rp = qkv + (size_t)row * 2048;
  f32x8v x = *(const f32x8v*)(rp + c);
  int po = (d < 32) ? c + 32 : c - 32;
  float sgn = (d < 32) ? -1.f : 1.f;
  f32x8v xr = *(const f32x8v*)(rp + po);
  f32x8v cc = *(const f32x8v*)(cs + t * 64 + d);
  f32x8v ss = *(const f32x8v*)(sn + t * 64 + d);
  f32x8v val = x * cc + (xr * sgn) * ss;
  float scale = (c < 1024) ? 0.125f : 1.0f;
  uint4 ov;
  ov.x = pk2(val[0] * scale, val[1] * scale);
  ov.y = pk2(val[2] * scale, val[3] * scale);
  ov.z = pk2(val[4] * scale, val[5] * scale);
  ov.w = pk2(val[6] * scale, val[7] * scale);
  if (c < 1024) {
    int h = c >> 6;
    *(uint4*)(Qb + ((size_t)(b * 16 + h) * 2048 + t) * 64 + d) = ov;
  } else {
    int kk = (c - 1024) >> 6;
    *(uint4*)(Kb + ((size_t)(b * 8 + kk) * 2048 + t) * 64 + d) = ov;
  }
}

// ------------- V transpose: qkv fp32 V-part -> Vt[b*8+kh][64][2048] bf16 -------------
__global__ __launch_bounds__(256) void k_vtrans(const float* __restrict__ qkv, u16* __restrict__ Vt) {
  __shared__ u16 tile[64][65];
  int blk = blockIdx.x;
  int t0 = (blk & 31) * 64;
  int bh = blk >> 5;  // b*8+kh
  int tx = threadIdx.x & 63, ty = threadIdx.x >> 6;
  const float* src = qkv + (size_t)((bh >> 3) * 2048 + t0) * 2048 + 1536 + (bh & 7) * 64;
#pragma unroll
  for (int i = 0; i < 64; i += 4)
    tile[ty + i][tx] = f2b(src[(size_t)(ty + i) * 2048 + tx]);
  __syncthreads();
  u16* dst = Vt + (size_t)bh * 64 * 2048 + t0;
#pragma unroll
  for (int i = 0; i < 64; i += 4)
    dst[(size_t)(ty + i) * 2048 + tx] = tile[tx][ty + i];
}

// ------------- causal flash attention v3: split-KV 2-way, 32x32 MFMA, 4 waves/SIMD -------------
// Each (bh,qt) unit = 2 waves (contiguous kv-tile halves), merged in LDS.
__global__ __launch_bounds__(256, 4) void k_flash3(const u16* __restrict__ Qb, const u16* __restrict__ Kb,
                                                   const u16* __restrict__ Vt, u16* __restrict__ Ob) {
  __shared__ float mbuf[2][64][33];
  __shared__ float mlm[2][2][64];
  __shared__ u32 otile[2][32 * 36];
  const int tid = threadIdx.x;
  const int l = tid & 63, w = tid >> 6;
  const int u = w >> 1, s = w & 1;
  const int uid = blockIdx.x * 2 + u;  // 2048 q-units
  const int bh = uid & 31;
  const int qt = 63 - (uid >> 5);      // descending work: long units launch first
  const int b = bh >> 4, h = bh & 15, kh = h >> 1;
  const int q0 = qt * 32;
  const int lq = l & 31, hi = l >> 5;
  const int q = q0 + lq;

  const u16* Qp = Qb + ((size_t)(b * 16 + h) * 2048 + q) * 64 + hi * 8;
  const u16* Kp = Kb + (size_t)(b * 8 + kh) * 2048 * 64 + (size_t)lq * 64 + hi * 8;
  const u16* Vp = Vt + (size_t)(b * 8 + kh) * 64 * 2048 + (size_t)lq * 2048 + hi * 8;

  bf16x8 qf[4];
#pragma unroll
  for (int ks = 0; ks < 4; ks++) qf[ks] = *(const bf16x8*)(Qp + ks * 16);

  f32x16 oa[2] = {};
  float m = -3e38f, lsum = 0.f;
  const int nt = (qt + 2) >> 1;        // total kv tiles for this unit
  const int nh0 = (nt + 1) >> 1;
  const int tbeg = s ? nh0 : 0;
  const int tend = s ? nt : nh0;

  for (int t = tbeg; t < tend; t++) {
    const int kvb = t * 64;
    // ---- QK^T: S^T[kv][q], two 32-kv subtiles ----
    f32x16 s0 = {}, s1 = {};
    bf16x8 kf0[4], kf1[4];
#pragma unroll
    for (int ks = 0; ks < 4; ks++) {
      kf0[ks] = *(const bf16x8*)(Kp + (size_t)kvb * 64 + ks * 16);
      kf1[ks] = *(const bf16x8*)(Kp + (size_t)(kvb + 32) * 64 + ks * 16);
    }
    __builtin_amdgcn_s_setprio(1);
#pragma unroll
    for (int ks = 0; ks < 4; ks++) {
      s0 = __builtin_amdgcn_mfma_f32_32x32x16_bf16(kf0[ks], qf[ks], s0, 0, 0, 0);
      s1 = __builtin_amdgcn_mfma_f32_32x32x16_bf16(kf1[ks], qf[ks], s1, 0, 0, 0);
    }
    __builtin_amdgcn_s_setprio(0);

    // ---- V fragments issued early: latency hides under mask+softmax ----
    bf16x8 vf[2][2][2];
#pragma unroll
    for (int dt = 0; dt < 2; dt++)
#pragma unroll
      for (int n = 0; n < 2; n++) {
        vf[dt][n][0] = *(const bf16x8*)(Vp + dt * 65536 + kvb + n * 32);
        vf[dt][n][1] = *(const bf16x8*)(Vp + dt * 65536 + kvb + n * 32 + 16);
      }

    // ---- causal mask (diagonal tile only) ----
    if (t == nt - 1) {
#pragma unroll
      for (int r = 0; r < 16; r++) {
        int kvr = kvb + (r & 3) + 8 * (r >> 2) + 4 * hi;
        if (kvr > q) s0[r] = -3e38f;
        if (kvr + 32 > q) s1[r] = -3e38f;
      }
    }

    // ---- online softmax (per-lane row; partner lane l^32 holds the other 32 kv) ----
    float tr[16];
#pragma unroll
    for (int r = 0; r < 16; r++) tr[r] = fmaxf(s0[r], s1[r]);
#pragma unroll
    for (int st = 8; st >= 1; st >>= 1)
#pragma unroll
      for (int i = 0; i < st; i++) tr[i] = fmaxf(tr[i], tr[i + st]);
    float mx = fmaxf(tr[0], __shfl_xor(tr[0], 32, 64));
    float mnew = fmaxf(m, mx);
    float alpha = exp2f((m - mnew) * LOG2E);
    float mb = mnew * LOG2E;
#pragma unroll
    for (int r = 0; r < 16; r++) {
      s0[r] = exp2f(fmaf(s0[r], LOG2E, -mb));
      s1[r] = exp2f(fmaf(s1[r], LOG2E, -mb));
    }
#pragma unroll
    for (int r = 0; r < 16; r++) tr[r] = s0[r] + s1[r];
#pragma unroll
    for (int st = 8; st >= 1; st >>= 1)
#pragma unroll
      for (int i = 0; i < st; i++) tr[i] += tr[i + st];
    float ssum = tr[0] + __shfl_xor(tr[0], 32, 64);
    lsum = lsum * alpha + ssum;
    m = mnew;
#pragma unroll
    for (int r = 0; r < 16; r++) { oa[0][r] *= alpha; oa[1][r] *= alpha; }

    // ---- P -> bf16 B-fragments (pk2 + permlane32_swap), then PV: O^T += V^T · P ----
#pragma unroll
    for (int n = 0; n < 2; n++) {
      u32 aw[8];
#pragma unroll
      for (int j = 0; j < 8; j++) {
        float va = n ? s1[2 * j] : s0[2 * j];
        float vb = n ? s1[2 * j + 1] : s0[2 * j + 1];
        aw[j] = pk2(va, vb);
      }
      plswap(aw[0], aw[2]); plswap(aw[1], aw[3]);
      plswap(aw[4], aw[6]); plswap(aw[5], aw[7]);
      union { u32 uu[4]; bf16x8 v; } p0, p1;
#pragma unroll
      for (int j = 0; j < 4; j++) { p0.uu[j] = aw[j]; p1.uu[j] = aw[4 + j]; }
      __builtin_amdgcn_s_setprio(1);
#pragma unroll
      for (int dt = 0; dt < 2; dt++) {
        oa[dt] = __builtin_amdgcn_mfma_f32_32x32x16_bf16(vf[dt][n][0], p0.v, oa[dt], 0, 0, 0);
        oa[dt] = __builtin_amdgcn_mfma_f32_32x32x16_bf16(vf[dt][n][1], p1.v, oa[dt], 0, 0, 0);
      }
      __builtin_amdgcn_s_setprio(0);
    }
  }

  // ---- merge the two kv-splits of this unit ----
  if (s) {
    mlm[u][0][l] = m;
    mlm[u][1][l] = lsum;
#pragma unroll
    for (int r = 0; r < 16; r++) {
      mbuf[u][l][r] = oa[0][r];
      mbuf[u][l][16 + r] = oa[1][r];
    }
  }
  __syncthreads();
  if (!s) {
    float m1 = mlm[u][0][l], l1 = mlm[u][1][l];
    float ms = fmaxf(m, m1);
    float a0 = exp2f((m - ms) * LOG2E);
    float a1 = exp2f((m1 - ms) * LOG2E);
    float linv = 1.0f / (lsum * a0 + l1 * a1);
    float of[32];
#pragma unroll
    for (int r = 0; r < 16; r++) {
      of[r] = (oa[0][r] * a0 + mbuf[u][l][r] * a1) * linv;
      of[16 + r] = (oa[1][r] * a0 + mbuf[u][l][16 + r] * a1) * linv;
    }
    // ---- epilogue: transpose O^T -> O via LDS, coalesced store ----
    u32* ot = otile[u];
#pragma unroll
    for (int dt = 0; dt < 2; dt++)
#pragma unroll
      for (int r = 0; r < 16; r += 2) {
        int d = dt * 32 + (r & 3) + 8 * (r >> 2) + 4 * hi;
        ot[lq * 36 + (d >> 1)] =
            (u32)f2b(of[dt * 16 + r]) | ((u32)f2b(of[dt * 16 + r + 1]) << 16);
      }
    const u32* otr = otile[u];
#pragma unroll
    for (int i = 0; i < 16; i++) {
      int wd = i * 64 + l;
      int row = wd >> 5, col = wd & 31;
      u32 v = otr[row * 36 + col];
      *(u32*)(Ob + (size_t)(b * 2048 + q0 + row) * 1024 + h * 64 + col * 2) = v;
    }
  }
}

extern "C" void kernel_launch(void* const* d_in, const int* in_sizes, int n_in,
                              void* d_out, int out_size, void* d_ws, size_t ws_size,
                              hipStream_t stream) {
  const float* x = (const float*)d_in[0];
  const float* cs = (const float*)d_in[1];
  const float* sn = (const float*)d_in[2];
  const float* w_qkv = (const float*)d_in[3];
  const float* w_out = (const float*)d_in[4];
  float* out = (float*)d_out;
  char* ws = (char*)d_ws;

  u16* Xb   = (u16*)(ws + (size_t)(0u) );          // 8 MB  [4096][1024]
  u16* Wqt  = (u16*)(ws + ((size_t)8u << 20));     // 4 MB  [2048][1024]
  u16* Wot  = (u16*)(ws + ((size_t)12u << 20));    // 2 MB  [1024][1024]
  float* qkv = (float*)(ws + ((size_t)14u << 20)); // 32 MB [4096][2048]
  u16* Qb   = (u16*)(ws + ((size_t)46u << 20));    // 8 MB  [2][16][2048][64]
  u16* Kb   = (u16*)(ws + ((size_t)54u << 20));    // 4 MB  [2][8][2048][64]
  u16* Vt   = (u16*)(ws + ((size_t)58u << 20));    // 4 MB  [2][8][64][2048]
  u16* Ob   = (u16*)(ws + ((size_t)62u << 20));    // 8 MB  [4096][1024]

  k_cast<<<4096, 256, 0, stream>>>(x, Xb);
  k_transpose<<<dim3(2048 / 32, 1024 / 32), dim3(32, 8), 0, stream>>>(w_qkv, Wqt, 1024, 2048);
  k_transpose<<<dim3(1024 / 32, 1024 / 32), dim3(32, 8), 0, stream>>>(w_out, Wot, 1024, 1024);
  k_gemm_bt<2048, 1024><<<dim3(32, 16), 256, 0, stream>>>(Xb, Wqt, qkv);
  k_rope<<<3072, 256, 0, stream>>>(qkv, cs, sn, Qb, Kb);
  k_vtrans<<<512, 256, 0, stream>>>(qkv, Vt);
  k_flash3<<<1024, 256, 0, stream>>>(Qb, Kb, Vt, Ob);
  k_gemm_bt<1024, 1024><<<dim3(32, 8), 256, 0, stream>>>(Ob, Wot, out);
}

// Round 4
// 139.581 us; speedup vs baseline: 2.2343x; 1.2187x over previous
//
#include <hip/hip_runtime.h>

typedef unsigned short u16;
typedef unsigned int u32;
typedef short bf16x8 __attribute__((ext_vector_type(8)));
typedef float f32x4 __attribute__((ext_vector_type(4)));
typedef float f32x8v __attribute__((ext_vector_type(8)));
typedef float f32x16 __attribute__((ext_vector_type(16)));

#define LOG2E 1.44269504f

__device__ __forceinline__ u16 f2b(float f) {
  union { float f; unsigned u; } v; v.f = f;
  unsigned r = v.u + 0x7FFFu + ((v.u >> 16) & 1u);
  return (u16)(r >> 16);
}

__device__ __forceinline__ u32 pk2(float a, float b) {
  union { float f; u32 u; } x, y; x.f = a; y.f = b;
  return ((x.u + 0x8000u) >> 16) | ((y.u + 0x8000u) & 0xFFFF0000u);
}

__device__ __forceinline__ void plswap(u32& x, u32& y) {
#if __has_builtin(__builtin_amdgcn_permlane32_swap)
  typedef int v2i __attribute__((ext_vector_type(2)));
  v2i r = __builtin_amdgcn_permlane32_swap((int)x, (int)y, false, false);
  x = (u32)r[0]; y = (u32)r[1];
#else
  u32 sx = (u32)__shfl_xor((int)x, 32, 64);
  u32 sy = (u32)__shfl_xor((int)y, 32, 64);
  bool hi = (threadIdx.x & 63) >= 32;
  u32 nx = hi ? sy : x;
  u32 ny = hi ? y : sx;
  x = nx; y = ny;
#endif
}

// async global->LDS, 16B per lane; LDS dest must be wave-uniform base (HW adds lane*16)
__device__ __forceinline__ void gld16(const void* g, void* l) {
  __builtin_amdgcn_global_load_lds((const __attribute__((address_space(1))) void*)g,
                                   (__attribute__((address_space(3))) void*)l, 16, 0, 0);
}

// ---------------- cast x: fp32 -> bf16, 4 elems/thread ----------------
__global__ __launch_bounds__(256) void k_cast(const float* __restrict__ in, u16* __restrict__ out) {
  int i = blockIdx.x * 256 + threadIdx.x;
  float4 v = ((const float4*)in)[i];
  ushort4 o;
  o.x = f2b(v.x); o.y = f2b(v.y); o.z = f2b(v.z); o.w = f2b(v.w);
  ((ushort4*)out)[i] = o;
}

// ------------- transpose+cast weights: in[R][C] fp32 -> out[C][R] bf16 -------------
__global__ __launch_bounds__(256) void k_transpose(const float* __restrict__ in, u16* __restrict__ out,
                                                   int R, int C) {
  __shared__ float tile[32][33];
  int c0 = blockIdx.x * 32, r0 = blockIdx.y * 32;
  int tx = threadIdx.x, ty = threadIdx.y;
#pragma unroll
  for (int i = 0; i < 32; i += 8)
    tile[ty + i][tx] = in[(size_t)(r0 + ty + i) * C + c0 + tx];
  __syncthreads();
#pragma unroll
  for (int i = 0; i < 32; i += 8)
    out[(size_t)(c0 + ty + i) * R + r0 + tx] = f2b(tile[tx][ty + i]);
}

// ------------- GEMM: C[M][N] fp32 = A[M][K]bf16 * Bt[N][K]bf16^T, 128x128 tile -------------
template<int Nsz, int Ksz>
__global__ __launch_bounds__(256) void k_gemm_bt(const u16* __restrict__ A, const u16* __restrict__ Bt,
                                                 float* __restrict__ C) {
  __shared__ u16 As[128 * 32];
  __shared__ u16 Bs[128 * 32];
  const int tid = threadIdx.x;
  const int l = tid & 63, w = tid >> 6;
  const int wm = w >> 1, wn = w & 1;
  const int m0 = blockIdx.x * 128, n0 = blockIdx.y * 128;
  const int rg = l >> 4, cl = l & 15;
  f32x4 acc[4][4] = {};
  for (int k0 = 0; k0 < Ksz; k0 += 32) {
#pragma unroll
    for (int i = 0; i < 2; i++) {
      int c = tid + i * 256;
      int row = c >> 2, off = c & 3;
      uint4 va = *(const uint4*)(A + (size_t)(m0 + row) * Ksz + k0 + off * 8);
      uint4 vb = *(const uint4*)(Bt + (size_t)(n0 + row) * Ksz + k0 + off * 8);
      unsigned ba = (unsigned)((row * 64 + off * 16) ^ ((row & 7) << 4));
      *(uint4*)((char*)As + ba) = va;
      *(uint4*)((char*)Bs + ba) = vb;
    }
    __syncthreads();
    bf16x8 aF[4], bF[4];
#pragma unroll
    for (int m = 0; m < 4; m++) {
      int row = wm * 64 + m * 16 + cl;
      unsigned ba = (unsigned)((row * 64 + rg * 16) ^ ((row & 7) << 4));
      aF[m] = *(const bf16x8*)((char*)As + ba);
    }
#pragma unroll
    for (int n = 0; n < 4; n++) {
      int row = wn * 64 + n * 16 + cl;
      unsigned ba = (unsigned)((row * 64 + rg * 16) ^ ((row & 7) << 4));
      bF[n] = *(const bf16x8*)((char*)Bs + ba);
    }
#pragma unroll
    for (int m = 0; m < 4; m++)
#pragma unroll
      for (int n = 0; n < 4; n++)
        acc[m][n] = __builtin_amdgcn_mfma_f32_16x16x32_bf16(aF[m], bF[n], acc[m][n], 0, 0, 0);
    __syncthreads();
  }
#pragma unroll
  for (int m = 0; m < 4; m++)
#pragma unroll
    for (int n = 0; n < 4; n++)
#pragma unroll
      for (int r = 0; r < 4; r++)
        C[(size_t)(m0 + wm * 64 + m * 16 + rg * 4 + r) * Nsz + n0 + wn * 64 + n * 16 + cl] = acc[m][n][r];
}

// ------------- RoPE Q/K (vectorized x8); scatter to head-major bf16 (Q scaled by 1/8) -------------
__global__ __launch_bounds__(256) void k_rope(const float* __restrict__ qkv, const float* __restrict__ cs,
                                              const float* __restrict__ sn, u16* __restrict__ Qb,
                                              u16* __restrict__ Kb) {
  int idx = blockIdx.x * 256 + threadIdx.x;  // over 4096*192 8-elem chunks
  int c8 = idx % 192;
  int row = idx / 192;
  int c = c8 * 8;
  int b = row >> 11, t = row & 2047;
  int d = c & 63;
  const float* rp = qkv + (size_t)row * 2048;
  f32x8v x = *(const f32x8v*)(rp + c);
  int po = (d < 32) ? c + 32 : c - 32;
  float sgn = (d < 32) ? -1.f : 1.f;
  f32x8v xr = *(const f32x8v*)(rp + po);
  f32x8v cc = *(const f32x8v*)(cs + t * 64 + d);
  f32x8v ss = *(const f32x8v*)(sn + t * 64 + d);
  f32x8v val = x * cc + (xr * sgn) * ss;
  float scale = (c < 1024) ? 0.125f : 1.0f;
  uint4 ov;
  ov.x = pk2(val[0] * scale, val[1] * scale);
  ov.y = pk2(val[2] * scale, val[3] * scale);
  ov.z = pk2(val[4] * scale, val[5] * scale);
  ov.w = pk2(val[6] * scale, val[7] * scale);
  if (c < 1024) {
    int h = c >> 6;
    *(uint4*)(Qb + ((size_t)(b * 16 + h) * 2048 + t) * 64 + d) = ov;
  } else {
    int kk = (c - 1024) >> 6;
    *(uint4*)(Kb + ((size_t)(b * 8 + kk) * 2048 + t) * 64 + d) = ov;
  }
}

// ------------- V transpose: qkv fp32 V-part -> Vt[b*8+kh][64][2048] bf16 -------------
__global__ __launch_bounds__(256) void k_vtrans(const float* __restrict__ qkv, u16* __restrict__ Vt) {
  __shared__ u16 tile[64][65];
  int blk = blockIdx.x;
  int t0 = (blk & 31) * 64;
  int bh = blk >> 5;  // b*8+kh
  int tx = threadIdx.x & 63, ty = threadIdx.x >> 6;
  const float* src = qkv + (size_t)((bh >> 3) * 2048 + t0) * 2048 + 1536 + (bh & 7) * 64;
#pragma unroll
  for (int i = 0; i < 64; i += 4)
    tile[ty + i][tx] = f2b(src[(size_t)(ty + i) * 2048 + tx]);
  __syncthreads();
  u16* dst = Vt + (size_t)bh * 64 * 2048 + t0;
#pragma unroll
  for (int i = 0; i < 64; i += 4)
    dst[(size_t)(ty + i) * 2048 + tx] = tile[tx][ty + i];
}

// ------------- causal flash attention v4: 8-wave block, K/V in double-buffered LDS -------------
// block = (b,kh): 8 waves = 2 heads x 4 q-tiles {qg+16j}. K/V tiles (64kv x 64d) staged once
// per block via global_load_lds with pre-swizzled source (chunk ^= row&7); ds_read_b128
// fragments conflict-free. 2-barrier loop, counted vmcnt(2).
__global__ __launch_bounds__(512) void k_flash4(const u16* __restrict__ Qb, const u16* __restrict__ Kb,
                                                const u16* __restrict__ Vt, u16* __restrict__ Ob) {
  __shared__ u16 Ks[2][64 * 64];
  __shared__ u16 Vs[2][64 * 64];
  __shared__ u32 otile[8][32 * 36];
  const int tid = threadIdx.x;
  const int l = tid & 63, w = tid >> 6;
  const int bid = blockIdx.x;
  const int bkh = bid & 15, qg = bid >> 4;   // kh fastest: XCD x serves kh=x only (L2 locality)
  const int b = bkh >> 3, kh = bkh & 7;
  const int h = kh * 2 + (w & 1);
  const int qt = qg + 16 * (w >> 1);
  const int q0 = qt * 32;
  const int lq = l & 31, hi = l >> 5;
  const int q = q0 + lq;
  const int xr = lq & 7;

  // staging decode: 512 threads, row = tid>>3, source chunk pre-swizzled
  const int sr = tid >> 3;
  const int sc = (tid & 7) ^ (sr & 7);
  const u16* Ksrc = Kb + (size_t)(b * 8 + kh) * 2048 * 64 + (size_t)sr * 64 + sc * 8;
  const u16* Vsrc = Vt + (size_t)(b * 8 + kh) * 64 * 2048 + (size_t)sr * 2048 + sc * 8;

  const u16* Qp = Qb + ((size_t)(b * 16 + h) * 2048 + q) * 64 + hi * 8;

  const int nt_w = (q0 + 95) >> 6;          // tiles this wave computes
  const int NT = (qg * 32 + 1631) >> 6;     // tiles the block stages (= nt_w of qt=qg+48)

  // prologue: stage tile 0
  gld16(Ksrc, &Ks[0][w << 9]);
  gld16(Vsrc, &Vs[0][w << 9]);

  bf16x8 qf[4];
#pragma unroll
  for (int ks = 0; ks < 4; ks++) qf[ks] = *(const bf16x8*)(Qp + ks * 16);

  f32x16 oa[2] = {};
  float m = -3e38f, lsum = 0.f;

  for (int t = 0; t < NT; t++) {
    const int cur = t & 1;
    if (t + 1 < NT) {
      gld16(Ksrc + ((size_t)(t + 1) << 6) * 64, &Ks[cur ^ 1][w << 9]);
      gld16(Vsrc + ((size_t)(t + 1) << 6), &Vs[cur ^ 1][w << 9]);
      asm volatile("s_waitcnt vmcnt(2)" ::: "memory");
    } else {
      asm volatile("s_waitcnt vmcnt(0)" ::: "memory");
    }
    __builtin_amdgcn_s_barrier();
    asm volatile("" ::: "memory");

    if (t < nt_w) {
      const int kvb = t << 6;
      const u16* KL = Ks[cur];
      const u16* VL = Vs[cur];
      // K fragments (swizzled chunks; rows lq and lq+32 share lq&7)
      bf16x8 kf0[4], kf1[4];
#pragma unroll
      for (int ks = 0; ks < 4; ks++) {
        int cc = (((ks << 1) | hi) ^ xr) * 8;
        kf0[ks] = *(const bf16x8*)(KL + lq * 64 + cc);
        kf1[ks] = *(const bf16x8*)(KL + (lq + 32) * 64 + cc);
      }
      f32x16 s0 = {}, s1 = {};
      __builtin_amdgcn_s_setprio(1);
#pragma unroll
      for (int ks = 0; ks < 4; ks++) {
        s0 = __builtin_amdgcn_mfma_f32_32x32x16_bf16(kf0[ks], qf[ks], s0, 0, 0, 0);
        s1 = __builtin_amdgcn_mfma_f32_32x32x16_bf16(kf1[ks], qf[ks], s1, 0, 0, 0);
      }
      __builtin_amdgcn_s_setprio(0);

      // V fragments issued before softmax (latency hides under VALU)
      bf16x8 vf[2][2][2];
#pragma unroll
      for (int dt = 0; dt < 2; dt++)
#pragma unroll
        for (int n = 0; n < 2; n++)
#pragma unroll
          for (int s16 = 0; s16 < 2; s16++) {
            int cc = ((n * 4 + s16 * 2 + hi) ^ xr) * 8;
            vf[dt][n][s16] = *(const bf16x8*)(VL + (dt * 32 + lq) * 64 + cc);
          }

      // causal mask (diagonal tile only)
      if (t == nt_w - 1) {
#pragma unroll
        for (int r = 0; r < 16; r++) {
          int kvr = kvb + (r & 3) + 8 * (r >> 2) + 4 * hi;
          if (kvr > q) s0[r] = -3e38f;
          if (kvr + 32 > q) s1[r] = -3e38f;
        }
      }

      // online softmax (per-lane q-row; partner lane l^32 holds other 32 kv)
      float tr[16];
#pragma unroll
      for (int r = 0; r < 16; r++) tr[r] = fmaxf(s0[r], s1[r]);
#pragma unroll
      for (int st = 8; st >= 1; st >>= 1)
#pragma unroll
        for (int i = 0; i < st; i++) tr[i] = fmaxf(tr[i], tr[i + st]);
      float mx = fmaxf(tr[0], __shfl_xor(tr[0], 32, 64));
      float mnew = fmaxf(m, mx);
      float alpha = exp2f((m - mnew) * LOG2E);
      float mb = mnew * LOG2E;
#pragma unroll
      for (int r = 0; r < 16; r++) {
        s0[r] = exp2f(fmaf(s0[r], LOG2E, -mb));
        s1[r] = exp2f(fmaf(s1[r], LOG2E, -mb));
      }
#pragma unroll
      for (int r = 0; r < 16; r++) tr[r] = s0[r] + s1[r];
#pragma unroll
      for (int st = 8; st >= 1; st >>= 1)
#pragma unroll
        for (int i = 0; i < st; i++) tr[i] += tr[i + st];
      float ssum = tr[0] + __shfl_xor(tr[0], 32, 64);
      lsum = lsum * alpha + ssum;
      m = mnew;
#pragma unroll
      for (int r = 0; r < 16; r++) { oa[0][r] *= alpha; oa[1][r] *= alpha; }

      // P -> bf16 B-fragments (pk2 + permlane32_swap), then PV: O^T += V^T . P
#pragma unroll
      for (int n = 0; n < 2; n++) {
        u32 aw[8];
#pragma unroll
        for (int j = 0; j < 8; j++) {
          float va = n ? s1[2 * j] : s0[2 * j];
          float vb = n ? s1[2 * j + 1] : s0[2 * j + 1];
          aw[j] = pk2(va, vb);
        }
        plswap(aw[0], aw[2]); plswap(aw[1], aw[3]);
        plswap(aw[4], aw[6]); plswap(aw[5], aw[7]);
        union { u32 uu[4]; bf16x8 v; } p0, p1;
#pragma unroll
        for (int j = 0; j < 4; j++) { p0.uu[j] = aw[j]; p1.uu[j] = aw[4 + j]; }
        __builtin_amdgcn_s_setprio(1);
#pragma unroll
        for (int dt = 0; dt < 2; dt++) {
          oa[dt] = __builtin_amdgcn_mfma_f32_32x32x16_bf16(vf[dt][n][0], p0.v, oa[dt], 0, 0, 0);
          oa[dt] = __builtin_amdgcn_mfma_f32_32x32x16_bf16(vf[dt][n][1], p1.v, oa[dt], 0, 0, 0);
        }
        __builtin_amdgcn_s_setprio(0);
      }
    }

    asm volatile("" ::: "memory");
    __builtin_amdgcn_s_barrier();
  }

  // ---- epilogue: normalize, transpose O^T -> O via wave-private LDS, coalesced store ----
  float linv = 1.0f / lsum;
  u32* ot = otile[w];
#pragma unroll
  for (int dt = 0; dt < 2; dt++)
#pragma unroll
    for (int r = 0; r < 16; r += 2) {
      int d = dt * 32 + (r & 3) + 8 * (r >> 2) + 4 * hi;
      ot[lq * 36 + (d >> 1)] =
          (u32)f2b(oa[dt][r] * linv) | ((u32)f2b(oa[dt][r + 1] * linv) << 16);
    }
  const u32* otr = otile[w];
#pragma unroll
  for (int i = 0; i < 16; i++) {
    int wd = i * 64 + l;
    int row = wd >> 5, col = wd & 31;
    u32 v = otr[row * 36 + col];
    *(u32*)(Ob + (size_t)(b * 2048 + q0 + row) * 1024 + h * 64 + col * 2) = v;
  }
}

extern "C" void kernel_launch(void* const* d_in, const int* in_sizes, int n_in,
                              void* d_out, int out_size, void* d_ws, size_t ws_size,
                              hipStream_t stream) {
  const float* x = (const float*)d_in[0];
  const float* cs = (const float*)d_in[1];
  const float* sn = (const float*)d_in[2];
  const float* w_qkv = (const float*)d_in[3];
  const float* w_out = (const float*)d_in[4];
  float* out = (float*)d_out;
  char* ws = (char*)d_ws;

  u16* Xb   = (u16*)(ws + (size_t)(0u) );          // 8 MB  [4096][1024]
  u16* Wqt  = (u16*)(ws + ((size_t)8u << 20));     // 4 MB  [2048][1024]
  u16* Wot  = (u16*)(ws + ((size_t)12u << 20));    // 2 MB  [1024][1024]
  float* qkv = (float*)(ws + ((size_t)14u << 20)); // 32 MB [4096][2048]
  u16* Qb   = (u16*)(ws + ((size_t)46u << 20));    // 8 MB  [2][16][2048][64]
  u16* Kb   = (u16*)(ws + ((size_t)54u << 20));    // 4 MB  [2][8][2048][64]
  u16* Vt   = (u16*)(ws + ((size_t)58u << 20));    // 4 MB  [2][8][64][2048]
  u16* Ob   = (u16*)(ws + ((size_t)62u << 20));    // 8 MB  [4096][1024]

  k_cast<<<4096, 256, 0, stream>>>(x, Xb);
  k_transpose<<<dim3(2048 / 32, 1024 / 32), dim3(32, 8), 0, stream>>>(w_qkv, Wqt, 1024, 2048);
  k_transpose<<<dim3(1024 / 32, 1024 / 32), dim3(32, 8), 0, stream>>>(w_out, Wot, 1024, 1024);
  k_gemm_bt<2048, 1024><<<dim3(32, 16), 256, 0, stream>>>(Xb, Wqt, qkv);
  k_rope<<<3072, 256, 0, stream>>>(qkv, cs, sn, Qb, Kb);
  k_vtrans<<<512, 256, 0, stream>>>(qkv, Vt);
  k_flash4<<<256, 512, 0, stream>>>(Qb, Kb, Vt, Ob);
  k_gemm_bt<1024, 1024><<<dim3(32, 8), 256, 0, stream>>>(Ob, Wot, out);
}